// Round 8
// baseline (58.855 us; speedup 1.0000x reference)
//
#include <hip/hip_runtime.h>
#include <math.h>

// x: [32,3,512,512] f32.
// Two-phase per block (512 thr = 8 waves, 32 output rows, full 512 width):
//  Phase A: 34 mag rows (r0-1..r0+32) split across waves (w0-5: 4 rows,
//    w6-7: 5). Each lane computes mag for ITS OWN 8 cols from rolling
//    global x loads (vertical pair-sum trick), writes to LDS. Rows outside
//    the image are written as zeros (pool zero-padding). Each LDS row has
//    4 zero pad floats on each side (stride 520) so phase-B reads need no
//    edge masking.
//  Phase B: per wave 4 output rows; 12-float LDS reads (cols c0-2..c0+9),
//    rolling 3-row vertical sum, 8 pooled values/lane/row, f32 sum/sumsq,
//    deferred /9, double wave+block reduce -> parts.
// Grid: (16, 96). Mag computed 34/32 = 1.06x (was 1.875x in r7).

#define RPB 32
#define MROWS (RPB + 2)   // 34
#define ROWF 520          // 4 pad + 512 + 4 pad floats per LDS mag row

__global__ __launch_bounds__(512, 4) void sobel_pool_stats(
    const float* __restrict__ x, double* __restrict__ parts) {
  __shared__ float smag[MROWS * ROWF];   // 70720 B
  __shared__ double red[16];

  const int tid = threadIdx.x;
  const int lane = tid & 63;
  const int w = tid >> 6;                 // wave 0..7
  const int bc = blockIdx.y;              // 0..95
  const int r0 = blockIdx.x * RPB;
  const float* __restrict__ xb = x + (size_t)bc * (512 * 512);

  const int c0 = lane * 8;
  const int cl = (lane > 0) ? c0 - 2 : 0;     // 8B-aligned
  const int cr = (lane < 63) ? c0 + 8 : 504;  // 8B-aligned
  const float lmask = (lane > 0) ? 1.f : 0.f;
  const float rmask = (lane < 63) ? 1.f : 0.f;

  // global load x[r][c0-2..c0+9] (we use [1..10] = cols c0-1..c0+8)
  auto loadx = [&](int r, float* o) {
    if ((unsigned)r < 512u) {
      const float* row = xb + (size_t)r * 512;
      float2 L = *(const float2*)(row + cl);
      float4 u = *(const float4*)(row + c0);
      float4 v = *(const float4*)(row + c0 + 4);
      float2 R = *(const float2*)(row + cr);
      o[0] = L.x * lmask; o[1] = L.y * lmask;
      o[2] = u.x; o[3] = u.y; o[4] = u.z; o[5] = u.w;
      o[6] = v.x; o[7] = v.y; o[8] = v.z; o[9] = v.w;
      o[10] = R.x * rmask; o[11] = R.y * rmask;
    } else {
#pragma unroll
      for (int j = 0; j < 12; ++j) o[j] = 0.f;
    }
  };

  // ---- Phase A: compute mag rows m0..m0+nrows-1 into LDS ----
  const int m0 = (w < 6) ? 4 * w : 24 + 5 * (w - 6);

  float S[12], X[12];   // rolling: S = x[rm-1]+x[rm], X = x[rm]
  {
    float t0[12], t1[12];
    loadx(r0 - 2 + m0, t0);
    loadx(r0 - 1 + m0, t1);
#pragma unroll
    for (int k = 1; k <= 10; ++k) S[k] = t0[k] + t1[k];
#pragma unroll
    for (int k = 1; k <= 10; ++k) X[k] = t1[k];
  }

  auto magrow = [&](int m) {
    const int rm = r0 - 1 + m;            // image row of mag row m
    float xn[12];
    loadx(rm + 1, xn);
    float S2[12];
#pragma unroll
    for (int k = 1; k <= 10; ++k) S2[k] = X[k] + xn[k];
    float* dst = &smag[m * ROWF];
    if ((unsigned)rm < 512u) {            // wave-uniform branch
      float aa[12], bb[12];
#pragma unroll
      for (int k = 1; k <= 10; ++k) { aa[k] = S[k] + S2[k]; bb[k] = S[k] - S2[k]; }
      float mg[8];
#pragma unroll
      for (int j = 0; j < 8; ++j) {
        float gx = aa[j + 1] - aa[j + 3];                       // horiz [1,0,-1]
        float gy = (bb[j + 1] + bb[j + 3]) + 2.f * bb[j + 2];   // horiz [1,2,1]
        mg[j] = __builtin_amdgcn_sqrtf(gx * gx + gy * gy + 1e-6f);
      }
      *(float4*)(dst + 4 + c0) = make_float4(mg[0], mg[1], mg[2], mg[3]);
      *(float4*)(dst + 8 + c0) = make_float4(mg[4], mg[5], mg[6], mg[7]);
    } else {
      float4 z = make_float4(0.f, 0.f, 0.f, 0.f);
      *(float4*)(dst + 4 + c0) = z;
      *(float4*)(dst + 8 + c0) = z;
    }
    // zero the row's pads (cols -4..-1 and 512..515)
    if (lane == 0) *(float4*)(dst) = make_float4(0.f, 0.f, 0.f, 0.f);
    if (lane == 1) *(float4*)(dst + 516) = make_float4(0.f, 0.f, 0.f, 0.f);
#pragma unroll
    for (int k = 1; k <= 10; ++k) { S[k] = S2[k]; X[k] = xn[k]; }
  };

#pragma unroll
  for (int i = 0; i < 4; ++i) magrow(m0 + i);
  if (w >= 6) magrow(m0 + 4);

  __syncthreads();

  // ---- Phase B: pool 4 output rows per wave ----
  // mag row m holds image row r0-1+m; pool row R0+i needs m = 4w+i .. 4w+i+2
  auto readm = [&](int m, float* o) {
    const float* base = &smag[m * ROWF + 2 + c0];   // cols c0-2..c0+9
    float2 L = *(const float2*)(base);
    float4 u = *(const float4*)(base + 2);
    float4 v = *(const float4*)(base + 6);
    float2 R = *(const float2*)(base + 10);
    o[0] = L.x; o[1] = L.y;
    o[2] = u.x; o[3] = u.y; o[4] = u.z; o[5] = u.w;
    o[6] = v.x; o[7] = v.y; o[8] = v.z; o[9] = v.w;
    o[10] = R.x; o[11] = R.y;
  };

  float A[12], B[12], N[12];
  readm(4 * w, A);
  readm(4 * w + 1, B);
  float s = 0.f, ss = 0.f;
#pragma unroll
  for (int i = 0; i < 4; ++i) {
    readm(4 * w + 2 + i, N);
    float cs[11];
#pragma unroll
    for (int k = 1; k <= 10; ++k) cs[k] = (A[k] + N[k]) + B[k];
#pragma unroll
    for (int j = 0; j < 8; ++j) {
      float t = (cs[j + 1] + cs[j + 3]) + cs[j + 2];
      s += t;
      ss = fmaf(t, t, ss);
    }
#pragma unroll
    for (int k = 1; k <= 10; ++k) { A[k] = B[k]; B[k] = N[k]; }
  }

  // wave reduce in double; fold deferred /9, /81
  double ds = (double)s * (1.0 / 9.0);
  double dss = (double)ss * (1.0 / 81.0);
  for (int off = 32; off > 0; off >>= 1) {
    ds += __shfl_down(ds, off);
    dss += __shfl_down(dss, off);
  }
  if (lane == 0) { red[w * 2] = ds; red[w * 2 + 1] = dss; }
  __syncthreads();
  if (tid == 0) {
    double Sb = 0.0, SSb = 0.0;
#pragma unroll
    for (int q = 0; q < 8; ++q) { Sb += red[q * 2]; SSb += red[q * 2 + 1]; }
    size_t idx = ((size_t)bc * 16 + blockIdx.x) * 2;
    parts[idx] = Sb;
    parts[idx + 1] = SSb;
  }
}

// Reduce 16 block-partials per (b,c), feats [32,6]=[m0,s0,m1,s1,m2,s2], MLP.
__global__ __launch_bounds__(256) void stats_mlp(
    const double* __restrict__ parts,
    const float* __restrict__ w1, const float* __restrict__ b1,
    const float* __restrict__ w2, const float* __restrict__ b2,
    float* __restrict__ out) {
  __shared__ float feats[32 * 6];
  __shared__ float hbuf[32 * 32];
  const int tid = threadIdx.x;

  if (tid < 96) {
    int b = tid / 3;
    int ch = tid - b * 3;
    double s = 0.0, ss = 0.0;
    const double* p = parts + (size_t)tid * 32;  // 16 blocks * 2 doubles
#pragma unroll
    for (int t = 0; t < 16; ++t) {
      s += p[2 * t];
      ss += p[2 * t + 1];
    }
    const double N = 262144.0;
    double mean = s / N;
    double var = (ss - s * s / N) / (N - 1.0);
    if (var < 0.0) var = 0.0;
    feats[b * 6 + 2 * ch] = (float)mean;
    feats[b * 6 + 2 * ch + 1] = (float)sqrt(var);
  }
  __syncthreads();

  for (int idx = tid; idx < 32 * 32; idx += 256) {
    int i = idx >> 5, j = idx & 31;
    float acc = b1[j];
#pragma unroll
    for (int k = 0; k < 6; ++k) acc += feats[i * 6 + k] * w1[j * 6 + k];
    hbuf[idx] = acc > 0.f ? acc : 0.f;
  }
  __syncthreads();

  for (int idx = tid; idx < 2048; idx += 256) {
    int i = idx >> 6, o = idx & 63;
    float acc = b2[o];
#pragma unroll
    for (int j = 0; j < 32; ++j) acc += hbuf[i * 32 + j] * w2[o * 32 + j];
    out[idx] = acc;
  }
}

extern "C" void kernel_launch(void* const* d_in, const int* in_sizes, int n_in,
                              void* d_out, int out_size, void* d_ws, size_t ws_size,
                              hipStream_t stream) {
  const float* x = (const float*)d_in[0];
  const float* w1 = (const float*)d_in[1];
  const float* b1 = (const float*)d_in[2];
  const float* w2 = (const float*)d_in[3];
  const float* b2 = (const float*)d_in[4];
  float* out = (float*)d_out;
  double* parts = (double*)d_ws;  // 96*16*2 doubles = 24576 B

  dim3 grid(16, 96);
  sobel_pool_stats<<<grid, 512, 0, stream>>>(x, parts);
  stats_mlp<<<1, 256, 0, stream>>>(parts, w1, b1, w2, b2, out);
}

// Round 9
// 33.172 us; speedup vs baseline: 1.7743x; 1.7743x over previous
//
#include <hip/hip_runtime.h>
#include <math.h>

// x: [32,3,512,512] f32.
// Register-only row sweep, no LDS, no barriers in stage 1.
// Each lane owns 8 cols (2 aligned float4 loads/row, wave spans 512 cols).
// Sobel separable via rolling vertical pair-sums: S = x[r-1]+x[r], X = x[r];
//   S2 = X + x[r+1]; a = S+S2 (vert [1,2,1]); b = S-S2 (vert [1,0,-1]);
//   gx = a(c-1)-a(c+1), gy = b(c-1)+2b(c)+b(c+1).
// Horizontal halo via 4 shuffles per mag row + 2 per pool row (conflict-free
// DS pipe; r8 showed lane-strided LDS is inherently 2x bank-conflicted).
// mag = v_sqrt_f32 (builtin), zeroed outside image (pool zero-padding).
// 3x3 pool, deferred /9; f32 per-row accumulation -> per-wave double partial.
// 12 output rows per wave; chunks 0..43 per (b,c) (43 real, 1 fully-masked
// dummy so blocks stay 4 waves). Grid: (11, 96) x 256 = 4224 waves.

__global__ __launch_bounds__(256) void sobel_pool_stats(
    const float* __restrict__ x, double* __restrict__ parts) {
  const int tid = threadIdx.x;
  const int lane = tid & 63;
  const int w = tid >> 6;
  const int bc = blockIdx.y;                 // 0..95
  const int chunk = blockIdx.x * 4 + w;      // 0..43
  const int row0 = chunk * 12;

  const float* __restrict__ xb = x + (size_t)bc * (512 * 512) + lane * 8;

  auto load8 = [&](int r, float* o) {
    if ((unsigned)r < 512u) {                // wave-uniform branch
      const float* p = xb + (size_t)r * 512;
      float4 u = *(const float4*)(p);
      float4 v = *(const float4*)(p + 4);
      o[0] = u.x; o[1] = u.y; o[2] = u.z; o[3] = u.w;
      o[4] = v.x; o[5] = v.y; o[6] = v.z; o[7] = v.w;
    } else {
#pragma unroll
      for (int k = 0; k < 8; ++k) o[k] = 0.f;
    }
  };

  float S[8], X[8];
  {
    float t0[8], t1[8];
    load8(row0 - 2, t0);
    load8(row0 - 1, t1);
#pragma unroll
    for (int k = 0; k < 8; ++k) { S[k] = t0[k] + t1[k]; X[k] = t1[k]; }
  }

  // Emit mag row rm (consumes x[rm+1]); advances S,X. mg=0 if rm OOB.
  auto magstep = [&](int rm, float* mg) {
    float xn[8], S2[8], a[8], b[8];
    load8(rm + 1, xn);
#pragma unroll
    for (int k = 0; k < 8; ++k) S2[k] = X[k] + xn[k];
#pragma unroll
    for (int k = 0; k < 8; ++k) { a[k] = S[k] + S2[k]; b[k] = S[k] - S2[k]; }
    float aL = __shfl_up(a[7], 1), aR = __shfl_down(a[0], 1);
    float bL = __shfl_up(b[7], 1), bR = __shfl_down(b[0], 1);
    if (lane == 0)  { aL = 0.f; bL = 0.f; }   // image col -1 = 0
    if (lane == 63) { aR = 0.f; bR = 0.f; }   // image col 512 = 0
    const float rmask = ((unsigned)rm < 512u) ? 1.f : 0.f;
#pragma unroll
    for (int j = 0; j < 8; ++j) {
      float am = j ? a[j - 1] : aL;
      float ap = (j < 7) ? a[j + 1] : aR;
      float bm = j ? b[j - 1] : bL;
      float bp = (j < 7) ? b[j + 1] : bR;
      float gx = am - ap;                      // horiz [1,0,-1]
      float gy = fmaf(2.f, b[j], bm + bp);     // horiz [1,2,1]
      float m2 = fmaf(gx, gx, 1e-6f);
      m2 = fmaf(gy, gy, m2);
      mg[j] = __builtin_amdgcn_sqrtf(m2) * rmask;
    }
#pragma unroll
    for (int k = 0; k < 8; ++k) { S[k] = S2[k]; X[k] = xn[k]; }
  };

  float MM[8], MC[8], MP[8];
  magstep(row0 - 1, MM);
  magstep(row0, MC);

  float s = 0.f, ss = 0.f;
#pragma unroll
  for (int i = 0; i < 12; ++i) {
    magstep(row0 + 1 + i, MP);               // mag[r+1]
    if ((unsigned)(row0 + i) < 512u) {       // wave-uniform: real output row
      float cs[8];
#pragma unroll
      for (int k = 0; k < 8; ++k) cs[k] = (MM[k] + MP[k]) + MC[k];
      float csL = __shfl_up(cs[7], 1), csR = __shfl_down(cs[0], 1);
      if (lane == 0) csL = 0.f;
      if (lane == 63) csR = 0.f;
#pragma unroll
      for (int j = 0; j < 8; ++j) {
        float cm = j ? cs[j - 1] : csL;
        float cp = (j < 7) ? cs[j + 1] : csR;
        float t = (cm + cp) + cs[j];
        s += t;
        ss = fmaf(t, t, ss);
      }
    }
#pragma unroll
    for (int k = 0; k < 8; ++k) { MM[k] = MC[k]; MC[k] = MP[k]; }
  }

  // per-wave double reduction; fold deferred /9, /81
  double ds = (double)s * (1.0 / 9.0);
  double dss = (double)ss * (1.0 / 81.0);
  for (int off = 32; off > 0; off >>= 1) {
    ds += __shfl_down(ds, off);
    dss += __shfl_down(dss, off);
  }
  if (lane == 0) {
    size_t idx = ((size_t)bc * 44 + chunk) * 2;
    parts[idx] = ds;
    parts[idx + 1] = dss;
  }
}

// Reduce 44 wave-partials per (b,c), feats [32,6]=[m0,s0,m1,s1,m2,s2], MLP.
__global__ __launch_bounds__(256) void stats_mlp(
    const double* __restrict__ parts,
    const float* __restrict__ w1, const float* __restrict__ b1,
    const float* __restrict__ w2, const float* __restrict__ b2,
    float* __restrict__ out) {
  __shared__ float feats[32 * 6];
  __shared__ float hbuf[32 * 32];
  const int tid = threadIdx.x;

  if (tid < 96) {
    int b = tid / 3;
    int ch = tid - b * 3;
    double s = 0.0, ss = 0.0;
    const double* p = parts + (size_t)tid * 88;  // 44 waves * 2 doubles
#pragma unroll
    for (int t = 0; t < 44; ++t) {
      s += p[2 * t];
      ss += p[2 * t + 1];
    }
    const double N = 262144.0;
    double mean = s / N;
    double var = (ss - s * s / N) / (N - 1.0);
    if (var < 0.0) var = 0.0;
    feats[b * 6 + 2 * ch] = (float)mean;
    feats[b * 6 + 2 * ch + 1] = (float)sqrt(var);
  }
  __syncthreads();

  for (int idx = tid; idx < 32 * 32; idx += 256) {
    int i = idx >> 5, j = idx & 31;
    float acc = b1[j];
#pragma unroll
    for (int k = 0; k < 6; ++k) acc += feats[i * 6 + k] * w1[j * 6 + k];
    hbuf[idx] = acc > 0.f ? acc : 0.f;
  }
  __syncthreads();

  for (int idx = tid; idx < 2048; idx += 256) {
    int i = idx >> 6, o = idx & 63;
    float acc = b2[o];
#pragma unroll
    for (int j = 0; j < 32; ++j) acc += hbuf[i * 32 + j] * w2[o * 32 + j];
    out[idx] = acc;
  }
}

extern "C" void kernel_launch(void* const* d_in, const int* in_sizes, int n_in,
                              void* d_out, int out_size, void* d_ws, size_t ws_size,
                              hipStream_t stream) {
  const float* x = (const float*)d_in[0];
  const float* w1 = (const float*)d_in[1];
  const float* b1 = (const float*)d_in[2];
  const float* w2 = (const float*)d_in[3];
  const float* b2 = (const float*)d_in[4];
  float* out = (float*)d_out;
  double* parts = (double*)d_ws;  // 96*44*2 doubles = 67584 B

  dim3 grid(11, 96);
  sobel_pool_stats<<<grid, 256, 0, stream>>>(x, parts);
  stats_mlp<<<1, 256, 0, stream>>>(parts, w1, b1, w2, b2, out);
}